// Round 21
// baseline (159.041 us; speedup 1.0000x reference)
//
#include <hip/hip_runtime.h>
#include <hip/hip_bf16.h>

// CCAM (fp32 in/out): x (16,1024,64,64), martx (4096,64).
// rows = B*C = 16384, N = 4096 spatial, KDIM = 64.
// energy[r][k] = sum_n x[r][n] * M[n][k]           (GEMM1, K=4096)
// att = softmax(alpha * (rowmax(energy) - energy))  (64-wide)
// out[r][n] = gamma * sum_k att[r][k]*M[n][k] + x[r][n]
//
// Round-21: round-19 (126.6 us best) + K-SLICED stage||ph1 pipeline.
// Stage in four 1024-col chunks; in slot q every wave issues chunk q+1's
// loads, then waves with kq==q run their FULL ph1 (A-data complete since the
// previous barrier) under those in-flight loads, then ds_write chunk q+1.
// Ph1's 16 wave-us now overlap stage chunks 1-3 instead of serializing.
// Ph2/ph3/store = round-19 verbatim. ph1's first B-frags hoisted to kernel
// top (compiler can't hoist loads across s_barrier).

using frag_ab = __attribute__((ext_vector_type(8))) short;   // 8 bf16
using f32x4   = __attribute__((ext_vector_type(4))) float;   // MFMA C/D + nt I/O

#define MFMA16(a, b, c) __builtin_amdgcn_mfma_f32_16x16x32_bf16((a), (b), (c), 0, 0, 0)

static __device__ __forceinline__ unsigned short f2bf_bits(float f) {
    __hip_bfloat16 h = __float2bfloat16(f);
    return *reinterpret_cast<const unsigned short*>(&h);
}
static __device__ __forceinline__ float bf2f(unsigned short u) {
    return __uint_as_float(((unsigned)u) << 16);
}
static __device__ __forceinline__ frag_ab load_frag(const __hip_bfloat16* p) {
    return *reinterpret_cast<const frag_ab*>(p);
}
static __device__ __forceinline__ frag_ab cvt2(float4 a, float4 b) {
    frag_ab r;
    r[0] = (short)f2bf_bits(a.x); r[1] = (short)f2bf_bits(a.y);
    r[2] = (short)f2bf_bits(a.z); r[3] = (short)f2bf_bits(a.w);
    r[4] = (short)f2bf_bits(b.x); r[5] = (short)f2bf_bits(b.y);
    r[6] = (short)f2bf_bits(b.z); r[7] = (short)f2bf_bits(b.w);
    return r;
}

// -------- kernel 0: build frag-linear B banks (unchanged, validated) --------
// MtF  (512 frags x 1 KB): frag f = slot*4+t, elem (lane,j) = M[32*slot+8g+j][16t+r15]
// MbfF (512 frags x 1 KB): frag f = nt*2+h,   elem (lane,j) = M[16nt+r15][32h+8g+j]
__global__ __launch_bounds__(256) void prep_frags(
        const float* __restrict__ M,
        __hip_bfloat16* __restrict__ MtF, __hip_bfloat16* __restrict__ MbfF) {
    const int w    = threadIdx.x >> 6;
    const int lane = threadIdx.x & 63;
    const int g    = lane >> 4;
    const int r15  = lane & 15;
    const int f    = blockIdx.x * 4 + w;    // 0..1023
    if (f < 512) {
        const int slot = f >> 2, t = f & 3;
        frag_ab fr;
#pragma unroll
        for (int j = 0; j < 8; ++j)
            fr[j] = (short)f2bf_bits(M[(size_t)(32 * slot + 8 * g + j) * 64 + 16 * t + r15]);
        *reinterpret_cast<frag_ab*>(MtF + ((size_t)f * 64 + lane) * 8) = fr;
    } else {
        const int f2 = f - 512;
        const float* src = M + (size_t)(16 * (f2 >> 1) + r15) * 64 + 32 * (f2 & 1) + 8 * g;
        float4 a = *reinterpret_cast<const float4*>(src);
        float4 b = *reinterpret_cast<const float4*>(src + 4);
        *reinterpret_cast<frag_ab*>(MbfF + ((size_t)f2 * 64 + lane) * 8) = cvt2(a, b);
    }
}

// -------- kernel 1: fused CCAM, 16-row blocks, K-sliced stage||ph1 ----------
// LDS 147712 B: x image 16 rows x 8208 B (bf16) = 131328;
//               Ep[4][4][16][16] f32 = 16384 at offset 131328.  1 block/CU.
__global__ __launch_bounds__(1024, 1) void ccam_fused(
        const float* __restrict__ x,
        const __hip_bfloat16* __restrict__ MtF,
        const __hip_bfloat16* __restrict__ MbfF,
        const float* __restrict__ aphal,
        const float* __restrict__ gamma,
        float* __restrict__ out) {
    __shared__ __align__(16) char smem[147712];
    float* Ep = (float*)(smem + 131328);   // [t1][kq][row][16] floats

    const int tid  = threadIdx.x;
    const int w    = tid >> 6;             // wave 0..15
    const int lane = tid & 63;
    const int g    = lane >> 4;
    const int r15  = lane & 15;
    const int rowbase = blockIdx.x * 16;

    const float alpha = aphal[0];
    const float gam   = gamma[0];

    const int t1 = w >> 2;                 // ph1 kdim-tile 0..3
    const int kq = w & 3;                  // ph1 K-quarter 0..3
    const int slot0 = kq * 32;             // MtF slot base for this wave

    // hoist ph1's first two B-frags (L2; independent of everything)
    frag_ab Bc = load_frag(MtF + (((size_t)slot0 * 4 + t1) * 64 + lane) * 8);
    frag_ab Bn = load_frag(MtF + (((size_t)(slot0 + 1) * 4 + t1) * 64 + lane) * 8);

    // ===== prologue: stage chunk 0 (cols 0-1023 of row w, nt loads) =====
    {
        const float* xr = x + (size_t)(rowbase + w) * 4096;
        char* dst = smem + w * 8208;
        f32x4 v[4];
#pragma unroll
        for (int i = 0; i < 4; ++i)
            v[i] = __builtin_nontemporal_load(
                reinterpret_cast<const f32x4*>(xr + i * 256 + 4 * lane));
#pragma unroll
        for (int i = 0; i < 4; ++i) {
            ushort4 u;
            u.x = f2bf_bits(v[i][0]); u.y = f2bf_bits(v[i][1]);
            u.z = f2bf_bits(v[i][2]); u.w = f2bf_bits(v[i][3]);
            *reinterpret_cast<ushort4*>(dst + (i * 256 + 4 * lane) * 2) = u;
        }
    }
    __syncthreads();   // chunk 0 resident

    // ===== slots q=0..3: stage chunk q+1  ||  ph1 for waves kq==q =====
#pragma unroll
    for (int q = 0; q < 4; ++q) {
        f32x4 v0, v1, v2, v3;
        if (q < 3) {   // 1. issue chunk q+1 loads (fly under ph1 below)
            const float* xr = x + (size_t)(rowbase + w) * 4096 + (q + 1) * 1024;
            v0 = __builtin_nontemporal_load(reinterpret_cast<const f32x4*>(xr + 0 * 256 + 4 * lane));
            v1 = __builtin_nontemporal_load(reinterpret_cast<const f32x4*>(xr + 1 * 256 + 4 * lane));
            v2 = __builtin_nontemporal_load(reinterpret_cast<const f32x4*>(xr + 2 * 256 + 4 * lane));
            v3 = __builtin_nontemporal_load(reinterpret_cast<const f32x4*>(xr + 3 * 256 + 4 * lane));
        }
        if (kq == q) {   // 2. this wave's ENTIRE ph1 (A-data complete at last barrier)
            f32x4 acc = {0.f, 0.f, 0.f, 0.f};
            const char* arow = smem + r15 * 8208;
            const int kbase = kq * 1024;
#pragma unroll 4
            for (int s = 0; s < 32; ++s) {
                frag_ab Bn2 = Bn;
                if (s < 30)
                    Bn2 = load_frag(MtF + (((size_t)(slot0 + s + 2) * 4 + t1) * 64 + lane) * 8);
                frag_ab A = *reinterpret_cast<const frag_ab*>(
                    arow + (kbase + 32 * s + 8 * g) * 2);
                acc = MFMA16(A, Bc, acc);
                Bc = Bn;
                Bn = Bn2;
            }
            // D: row = 4g+reg (x-row), col = r15 (kdim in tile t1)
#pragma unroll
            for (int reg = 0; reg < 4; ++reg)
                Ep[(((t1 * 4 + kq) * 16) + 4 * g + reg) * 16 + r15] = acc[reg];
        }
        if (q < 3) {   // 3. write chunk q+1 to the image
            char* dst = smem + w * 8208 + (q + 1) * 2048;
            ushort4 u;
            u.x = f2bf_bits(v0[0]); u.y = f2bf_bits(v0[1]);
            u.z = f2bf_bits(v0[2]); u.w = f2bf_bits(v0[3]);
            *reinterpret_cast<ushort4*>(dst + (0 * 256 + 4 * lane) * 2) = u;
            u.x = f2bf_bits(v1[0]); u.y = f2bf_bits(v1[1]);
            u.z = f2bf_bits(v1[2]); u.w = f2bf_bits(v1[3]);
            *reinterpret_cast<ushort4*>(dst + (1 * 256 + 4 * lane) * 2) = u;
            u.x = f2bf_bits(v2[0]); u.y = f2bf_bits(v2[1]);
            u.z = f2bf_bits(v2[2]); u.w = f2bf_bits(v2[3]);
            *reinterpret_cast<ushort4*>(dst + (2 * 256 + 4 * lane) * 2) = u;
            u.x = f2bf_bits(v3[0]); u.y = f2bf_bits(v3[1]);
            u.z = f2bf_bits(v3[2]); u.w = f2bf_bits(v3[3]);
            *reinterpret_cast<ushort4*>(dst + (3 * 256 + 4 * lane) * 2) = u;
        }
        __syncthreads();   // chunk q+1 resident; Ep[.. kq==q ..] written
    }

    // ===== phase 2: softmax; lane (g,r15) -> row r15, kdims 8g+j / 32+8g+j =====
    float elo[8], ehi[8];
    {
        const int t0  = g >> 1;
        const int off = 8 * (g & 1);
#pragma unroll
        for (int j = 0; j < 8; ++j) { elo[j] = 0.f; ehi[j] = 0.f; }
#pragma unroll
        for (int q = 0; q < 4; ++q) {
            const float* pl = Ep + ((t0 * 4 + q) * 16 + r15) * 16 + off;
            const float* ph = Ep + (((t0 + 2) * 4 + q) * 16 + r15) * 16 + off;
            float4 a0 = *reinterpret_cast<const float4*>(pl);
            float4 a1 = *reinterpret_cast<const float4*>(pl + 4);
            elo[0] += a0.x; elo[1] += a0.y; elo[2] += a0.z; elo[3] += a0.w;
            elo[4] += a1.x; elo[5] += a1.y; elo[6] += a1.z; elo[7] += a1.w;
            float4 c0 = *reinterpret_cast<const float4*>(ph);
            float4 c1 = *reinterpret_cast<const float4*>(ph + 4);
            ehi[0] += c0.x; ehi[1] += c0.y; ehi[2] += c0.z; ehi[3] += c0.w;
            ehi[4] += c1.x; ehi[5] += c1.y; ehi[6] += c1.z; ehi[7] += c1.w;
        }
    }
    float m = elo[0];
#pragma unroll
    for (int j = 1; j < 8; ++j) m = fmaxf(m, elo[j]);
#pragma unroll
    for (int j = 0; j < 8; ++j) m = fmaxf(m, ehi[j]);
    m = fmaxf(m, __shfl_xor(m, 16, 64));
    m = fmaxf(m, __shfl_xor(m, 32, 64));
#pragma unroll
    for (int j = 0; j < 8; ++j) { elo[j] = alpha * (m - elo[j]); ehi[j] = alpha * (m - ehi[j]); }
    float vm = elo[0];
#pragma unroll
    for (int j = 1; j < 8; ++j) vm = fmaxf(vm, elo[j]);
#pragma unroll
    for (int j = 0; j < 8; ++j) vm = fmaxf(vm, ehi[j]);
    vm = fmaxf(vm, __shfl_xor(vm, 16, 64));
    vm = fmaxf(vm, __shfl_xor(vm, 32, 64));
    float s = 0.f;
#pragma unroll
    for (int j = 0; j < 8; ++j) { elo[j] = __expf(elo[j] - vm); s += elo[j]; }
#pragma unroll
    for (int j = 0; j < 8; ++j) { ehi[j] = __expf(ehi[j] - vm); s += ehi[j]; }
    s += __shfl_xor(s, 16, 64);
    s += __shfl_xor(s, 32, 64);
    const float sc = gam / s;               // fold gamma into attention
    frag_ab A0, A1;   // A: row = r15, k = 8g+j (A0) / 32+8g+j (A1)
#pragma unroll
    for (int j = 0; j < 8; ++j) {
        A0[j] = (short)f2bf_bits(elo[j] * sc);
        A1[j] = (short)f2bf_bits(ehi[j] * sc);
    }

    // ===== phase 3: in-place RMW; wave w owns cols [256w, 256w+256) =====
#pragma unroll 1
    for (int gi = 0; gi < 4; ++gi) {
        const int grp = 4 * w + gi;        // 64-col group
        frag_ab B[4][2];
#pragma unroll
        for (int t = 0; t < 4; ++t)
#pragma unroll
            for (int h = 0; h < 2; ++h)
                B[t][h] = load_frag(MbfF + (((size_t)(4 * grp + t) * 2 + h) * 64 + lane) * 8);
        f32x4 d0 = {0.f, 0.f, 0.f, 0.f};
        f32x4 d1 = d0, d2 = d0, d3 = d0;
        d0 = MFMA16(A0, B[0][0], d0); d0 = MFMA16(A1, B[0][1], d0);
        d1 = MFMA16(A0, B[1][0], d1); d1 = MFMA16(A1, B[1][1], d1);
        d2 = MFMA16(A0, B[2][0], d2); d2 = MFMA16(A1, B[2][1], d2);
        d3 = MFMA16(A0, B[3][0], d3); d3 = MFMA16(A1, B[3][1], d3);
        const int colbase = grp * 64 + r15;
#pragma unroll
        for (int reg = 0; reg < 4; ++reg) {
            unsigned short* p =
                (unsigned short*)(smem + (4 * g + reg) * 8208) + colbase;
            p[ 0] = f2bf_bits(d0[reg] + bf2f(p[ 0]));
            p[16] = f2bf_bits(d1[reg] + bf2f(p[16]));
            p[32] = f2bf_bits(d2[reg] + bf2f(p[32]));
            p[48] = f2bf_bits(d3[reg] + bf2f(p[48]));
        }
    }
    __syncthreads();

    // ===== store: wave w streams row w out sequentially — NON-TEMPORAL =====
    {
        const char* srow = smem + w * 8208;
        float* orow = out + (size_t)(rowbase + w) * 4096;
#pragma unroll
        for (int i = 0; i < 16; ++i) {
            const int col = 256 * i + 4 * lane;
            ushort4 u = *reinterpret_cast<const ushort4*>(srow + col * 2);
            f32x4 v;
            v[0] = bf2f(u.x); v[1] = bf2f(u.y); v[2] = bf2f(u.z); v[3] = bf2f(u.w);
            __builtin_nontemporal_store(v, reinterpret_cast<f32x4*>(orow + col));
        }
    }
}

extern "C" void kernel_launch(void* const* d_in, const int* in_sizes, int n_in,
                              void* d_out, int out_size, void* d_ws, size_t ws_size,
                              hipStream_t stream) {
    const float* x     = (const float*)d_in[0];
    const float* M     = (const float*)d_in[1];
    const float* aphal = (const float*)d_in[2];
    const float* gamma = (const float*)d_in[3];
    __hip_bfloat16* MtF  = (__hip_bfloat16*)d_ws;                  // 512 KB
    __hip_bfloat16* MbfF = (__hip_bfloat16*)d_ws + 64 * 4096;      // 512 KB

    hipLaunchKernelGGL(prep_frags, dim3(256), dim3(256), 0, stream, M, MtF, MbfF);
    hipLaunchKernelGGL(ccam_fused, dim3(1024), dim3(1024), 0, stream,
                       x, MtF, MbfF, aphal, gamma, (float*)d_out);
}

// Round 22
// 126.457 us; speedup vs baseline: 1.2577x; 1.2577x over previous
//
#include <hip/hip_runtime.h>
#include <hip/hip_bf16.h>

// CCAM (fp32 in/out): x (16,1024,64,64), martx (4096,64).
// rows = B*C = 16384, N = 4096 spatial, KDIM = 64.
// energy[r][k] = sum_n x[r][n] * M[n][k]           (GEMM1, K=4096)
// att = softmax(alpha * (rowmax(energy) - energy))  (64-wide)
// out[r][n] = gamma * sum_k att[r][k]*M[n][k] + x[r][n]
//
// Round-22: REVERT to the round-19 winner (126.6 us), verbatim. Round 20
// (persistent+fused tail) and round 21 (K-sliced stage||ph1) both regressed:
// in this barrier-coupled structure, wave-partitioned overlap loses more to
// lockstep idling than it gains. r19 = 16-row blocks, whole-phase schedule,
// nt x loads + nt out stores, depth-2 B prefetch in ph1, all-lane RMW.

using frag_ab = __attribute__((ext_vector_type(8))) short;   // 8 bf16
using f32x4   = __attribute__((ext_vector_type(4))) float;   // MFMA C/D + nt I/O

#define MFMA16(a, b, c) __builtin_amdgcn_mfma_f32_16x16x32_bf16((a), (b), (c), 0, 0, 0)

static __device__ __forceinline__ unsigned short f2bf_bits(float f) {
    __hip_bfloat16 h = __float2bfloat16(f);
    return *reinterpret_cast<const unsigned short*>(&h);
}
static __device__ __forceinline__ float bf2f(unsigned short u) {
    return __uint_as_float(((unsigned)u) << 16);
}
static __device__ __forceinline__ frag_ab load_frag(const __hip_bfloat16* p) {
    return *reinterpret_cast<const frag_ab*>(p);
}
static __device__ __forceinline__ frag_ab cvt2(float4 a, float4 b) {
    frag_ab r;
    r[0] = (short)f2bf_bits(a.x); r[1] = (short)f2bf_bits(a.y);
    r[2] = (short)f2bf_bits(a.z); r[3] = (short)f2bf_bits(a.w);
    r[4] = (short)f2bf_bits(b.x); r[5] = (short)f2bf_bits(b.y);
    r[6] = (short)f2bf_bits(b.z); r[7] = (short)f2bf_bits(b.w);
    return r;
}

// -------- kernel 0: build frag-linear B banks (unchanged, validated) --------
// MtF  (512 frags x 1 KB): frag f = slot*4+t, elem (lane,j) = M[32*slot+8g+j][16t+r15]
// MbfF (512 frags x 1 KB): frag f = nt*2+h,   elem (lane,j) = M[16nt+r15][32h+8g+j]
__global__ __launch_bounds__(256) void prep_frags(
        const float* __restrict__ M,
        __hip_bfloat16* __restrict__ MtF, __hip_bfloat16* __restrict__ MbfF) {
    const int w    = threadIdx.x >> 6;
    const int lane = threadIdx.x & 63;
    const int g    = lane >> 4;
    const int r15  = lane & 15;
    const int f    = blockIdx.x * 4 + w;    // 0..1023
    if (f < 512) {
        const int slot = f >> 2, t = f & 3;
        frag_ab fr;
#pragma unroll
        for (int j = 0; j < 8; ++j)
            fr[j] = (short)f2bf_bits(M[(size_t)(32 * slot + 8 * g + j) * 64 + 16 * t + r15]);
        *reinterpret_cast<frag_ab*>(MtF + ((size_t)f * 64 + lane) * 8) = fr;
    } else {
        const int f2 = f - 512;
        const float* src = M + (size_t)(16 * (f2 >> 1) + r15) * 64 + 32 * (f2 & 1) + 8 * g;
        float4 a = *reinterpret_cast<const float4*>(src);
        float4 b = *reinterpret_cast<const float4*>(src + 4);
        *reinterpret_cast<frag_ab*>(MbfF + ((size_t)f2 * 64 + lane) * 8) = cvt2(a, b);
    }
}

// -------- kernel 1: fused CCAM, 16-row blocks -------------------------------
// LDS 147712 B: x image 16 rows x 8208 B (bf16) = 131328;
//               Ep[4][4][16][16] f32 = 16384 at offset 131328.  1 block/CU.
__global__ __launch_bounds__(1024, 1) void ccam_fused(
        const float* __restrict__ x,
        const __hip_bfloat16* __restrict__ MtF,
        const __hip_bfloat16* __restrict__ MbfF,
        const float* __restrict__ aphal,
        const float* __restrict__ gamma,
        float* __restrict__ out) {
    __shared__ __align__(16) char smem[147712];
    float* Ep = (float*)(smem + 131328);   // [t1][kq][row][16] floats

    const int tid  = threadIdx.x;
    const int w    = tid >> 6;             // wave 0..15
    const int lane = tid & 63;
    const int g    = lane >> 4;
    const int r15  = lane & 15;
    const int rowbase = blockIdx.x * 16;

    const float alpha = aphal[0];
    const float gam   = gamma[0];

    // ===== stage: wave w reads row w sequentially (nt), bf16 into LDS =====
    {
        const float* xr = x + (size_t)(rowbase + w) * 4096;
        char* dst = smem + w * 8208;
#pragma unroll
        for (int rnd = 0; rnd < 2; ++rnd) {
            f32x4 v[8];
#pragma unroll
            for (int i = 0; i < 8; ++i)
                v[i] = __builtin_nontemporal_load(
                    reinterpret_cast<const f32x4*>(xr + rnd * 2048 + i * 256 + 4 * lane));
#pragma unroll
            for (int i = 0; i < 8; ++i) {
                ushort4 u;
                u.x = f2bf_bits(v[i][0]); u.y = f2bf_bits(v[i][1]);
                u.z = f2bf_bits(v[i][2]); u.w = f2bf_bits(v[i][3]);
                *reinterpret_cast<ushort4*>(dst + (rnd * 2048 + i * 256 + 4 * lane) * 2) = u;
            }
        }
    }
    __syncthreads();

    // ===== phase 1: energy; wave = (kdim-tile t1, K-quarter kq), 32 MFMAs =====
    const int t1 = w >> 2;                 // 0..3
    const int kq = w & 3;                  // 0..3
    {
        f32x4 acc = {0.f, 0.f, 0.f, 0.f};
        const char* arow = smem + r15 * 8208;   // A row = r15 (16 distinct rows)
        const int kbase = kq * 1024;            // element offset within row
        const int slot0 = kq * 32;              // MtF slot base
        frag_ab Bc = load_frag(MtF + (((size_t)slot0 * 4 + t1) * 64 + lane) * 8);
        frag_ab Bn = load_frag(MtF + (((size_t)(slot0 + 1) * 4 + t1) * 64 + lane) * 8);
#pragma unroll 4
        for (int s = 0; s < 32; ++s) {
            frag_ab Bn2 = Bn;
            if (s < 30)
                Bn2 = load_frag(MtF + (((size_t)(slot0 + s + 2) * 4 + t1) * 64 + lane) * 8);
            frag_ab A = *reinterpret_cast<const frag_ab*>(
                arow + (kbase + 32 * s + 8 * g) * 2);
            acc = MFMA16(A, Bc, acc);
            Bc = Bn;
            Bn = Bn2;
        }
        // D: row = 4g+reg (x-row), col = r15 (kdim in tile t1); all lanes write
#pragma unroll
        for (int reg = 0; reg < 4; ++reg)
            Ep[(((t1 * 4 + kq) * 16) + 4 * g + reg) * 16 + r15] = acc[reg];
    }
    __syncthreads();

    // ===== phase 2: softmax; lane (g,r15) -> row r15, kdims 8g+j / 32+8g+j =====
    float elo[8], ehi[8];
    {
        const int t0  = g >> 1;
        const int off = 8 * (g & 1);
#pragma unroll
        for (int j = 0; j < 8; ++j) { elo[j] = 0.f; ehi[j] = 0.f; }
#pragma unroll
        for (int q = 0; q < 4; ++q) {
            const float* pl = Ep + ((t0 * 4 + q) * 16 + r15) * 16 + off;
            const float* ph = Ep + (((t0 + 2) * 4 + q) * 16 + r15) * 16 + off;
            float4 a0 = *reinterpret_cast<const float4*>(pl);
            float4 a1 = *reinterpret_cast<const float4*>(pl + 4);
            elo[0] += a0.x; elo[1] += a0.y; elo[2] += a0.z; elo[3] += a0.w;
            elo[4] += a1.x; elo[5] += a1.y; elo[6] += a1.z; elo[7] += a1.w;
            float4 c0 = *reinterpret_cast<const float4*>(ph);
            float4 c1 = *reinterpret_cast<const float4*>(ph + 4);
            ehi[0] += c0.x; ehi[1] += c0.y; ehi[2] += c0.z; ehi[3] += c0.w;
            ehi[4] += c1.x; ehi[5] += c1.y; ehi[6] += c1.z; ehi[7] += c1.w;
        }
    }
    float m = elo[0];
#pragma unroll
    for (int j = 1; j < 8; ++j) m = fmaxf(m, elo[j]);
#pragma unroll
    for (int j = 0; j < 8; ++j) m = fmaxf(m, ehi[j]);
    m = fmaxf(m, __shfl_xor(m, 16, 64));
    m = fmaxf(m, __shfl_xor(m, 32, 64));
#pragma unroll
    for (int j = 0; j < 8; ++j) { elo[j] = alpha * (m - elo[j]); ehi[j] = alpha * (m - ehi[j]); }
    float vm = elo[0];
#pragma unroll
    for (int j = 1; j < 8; ++j) vm = fmaxf(vm, elo[j]);
#pragma unroll
    for (int j = 0; j < 8; ++j) vm = fmaxf(vm, ehi[j]);
    vm = fmaxf(vm, __shfl_xor(vm, 16, 64));
    vm = fmaxf(vm, __shfl_xor(vm, 32, 64));
    float s = 0.f;
#pragma unroll
    for (int j = 0; j < 8; ++j) { elo[j] = __expf(elo[j] - vm); s += elo[j]; }
#pragma unroll
    for (int j = 0; j < 8; ++j) { ehi[j] = __expf(ehi[j] - vm); s += ehi[j]; }
    s += __shfl_xor(s, 16, 64);
    s += __shfl_xor(s, 32, 64);
    const float sc = gam / s;               // fold gamma into attention
    frag_ab A0, A1;   // A: row = r15, k = 8g+j (A0) / 32+8g+j (A1)
#pragma unroll
    for (int j = 0; j < 8; ++j) {
        A0[j] = (short)f2bf_bits(elo[j] * sc);
        A1[j] = (short)f2bf_bits(ehi[j] * sc);
    }

    // ===== phase 3: in-place RMW; wave w owns cols [256w, 256w+256) =====
    // D rows 0..15 all distinct: lane RMWs rows 4g+reg, 4 col-tiles (16/lane).
#pragma unroll 1
    for (int gi = 0; gi < 4; ++gi) {
        const int grp = 4 * w + gi;        // 0..63 (64-col group)
        frag_ab B[4][2];
#pragma unroll
        for (int t = 0; t < 4; ++t)
#pragma unroll
            for (int h = 0; h < 2; ++h)
                B[t][h] = load_frag(MbfF + (((size_t)(4 * grp + t) * 2 + h) * 64 + lane) * 8);
        f32x4 d0 = {0.f, 0.f, 0.f, 0.f};
        f32x4 d1 = d0, d2 = d0, d3 = d0;
        d0 = MFMA16(A0, B[0][0], d0); d0 = MFMA16(A1, B[0][1], d0);
        d1 = MFMA16(A0, B[1][0], d1); d1 = MFMA16(A1, B[1][1], d1);
        d2 = MFMA16(A0, B[2][0], d2); d2 = MFMA16(A1, B[2][1], d2);
        d3 = MFMA16(A0, B[3][0], d3); d3 = MFMA16(A1, B[3][1], d3);
        const int colbase = grp * 64 + r15;
#pragma unroll
        for (int reg = 0; reg < 4; ++reg) {
            unsigned short* p =
                (unsigned short*)(smem + (4 * g + reg) * 8208) + colbase;
            p[ 0] = f2bf_bits(d0[reg] + bf2f(p[ 0]));
            p[16] = f2bf_bits(d1[reg] + bf2f(p[16]));
            p[32] = f2bf_bits(d2[reg] + bf2f(p[32]));
            p[48] = f2bf_bits(d3[reg] + bf2f(p[48]));
        }
    }
    __syncthreads();

    // ===== store: wave w streams row w out sequentially — NON-TEMPORAL =====
    {
        const char* srow = smem + w * 8208;
        float* orow = out + (size_t)(rowbase + w) * 4096;
#pragma unroll
        for (int i = 0; i < 16; ++i) {
            const int col = 256 * i + 4 * lane;
            ushort4 u = *reinterpret_cast<const ushort4*>(srow + col * 2);
            f32x4 v;
            v[0] = bf2f(u.x); v[1] = bf2f(u.y); v[2] = bf2f(u.z); v[3] = bf2f(u.w);
            __builtin_nontemporal_store(v, reinterpret_cast<f32x4*>(orow + col));
        }
    }
}

extern "C" void kernel_launch(void* const* d_in, const int* in_sizes, int n_in,
                              void* d_out, int out_size, void* d_ws, size_t ws_size,
                              hipStream_t stream) {
    const float* x     = (const float*)d_in[0];
    const float* M     = (const float*)d_in[1];
    const float* aphal = (const float*)d_in[2];
    const float* gamma = (const float*)d_in[3];
    __hip_bfloat16* MtF  = (__hip_bfloat16*)d_ws;                  // 512 KB
    __hip_bfloat16* MbfF = (__hip_bfloat16*)d_ws + 64 * 4096;      // 512 KB

    hipLaunchKernelGGL(prep_frags, dim3(256), dim3(256), 0, stream, M, MtF, MbfF);
    hipLaunchKernelGGL(ccam_fused, dim3(1024), dim3(1024), 0, stream,
                       x, MtF, MbfF, aphal, gamma, (float*)d_out);
}